// Round 3
// baseline (144.445 us; speedup 1.0000x reference)
//
#include <hip/hip_runtime.h>

// Where2comm AttenFusion, ego-row-only, float4-over-pixels + nontemporal.
// x: (B=16, N=5, C=64, HW=25200) f32; out: (B, C, HW) f32.
// Per pixel p: dot[m] = <x[b,0,:,p], x[b,m,:,p]>/8; w = softmax(dot);
// out[b,:,p] = sum_m w[m]*x[b,m,:,p].
//
// Lane map: l&3 = pixel-group (4 lanes x 16B = 64B contiguous per plane),
// l>>2 = chan-lane (16 lanes x 4 channels). All global accesses are
// dwordx4 with the nt (nontemporal) hint — pure streaming, zero reuse,
// so L2 retention of either stream is waste.

#define B_ 16
#define N_ 5
#define C_ 64
#define HW_ 25200
#define PG_PER_IMG (HW_ / 4)   // 6300, divisible by 4 -> wave never straddles b

typedef float f4 __attribute__((ext_vector_type(4)));

__global__ __launch_bounds__(256) void where2comm_atten_kernel(
    const float* __restrict__ x, float* __restrict__ out)
{
    const int tid = blockIdx.x * 256 + threadIdx.x;
    const int l   = tid & 63;
    const int pg  = (tid >> 6) * 4 + (l & 3);   // global 4-pixel group
    const int cl  = l >> 2;                     // chan-lane 0..15
    const int b   = pg / PG_PER_IMG;
    const int p   = (pg - b * PG_PER_IMG) * 4;  // pixel offset in image (16B-aligned)

    const f4* xb = reinterpret_cast<const f4*>(
        x + (size_t)b * (N_ * C_ * HW_) + (size_t)(cl * 4) * HW_ + p);

    // Load 5 cavs x 4 channels x 4 pixels, all dwordx4 nt.
    f4 v[N_][4];
#pragma unroll
    for (int m = 0; m < N_; ++m)
#pragma unroll
        for (int j = 0; j < 4; ++j)
            v[m][j] = __builtin_nontemporal_load(
                reinterpret_cast<const f4*>(
                    reinterpret_cast<const float*>(xb) + (size_t)(m * C_ + j) * HW_));

    // Per-pixel partial dots over this lane's 4 channels.
    f4 d[N_];
#pragma unroll
    for (int m = 0; m < N_; ++m) {
        f4 acc = v[0][0] * v[m][0];
#pragma unroll
        for (int j = 1; j < 4; ++j) acc += v[0][j] * v[m][j];
        d[m] = acc;
    }

    // Reduce across the 16 chan-lanes (lane stride 4): masks 4,8,16,32.
#pragma unroll
    for (int mask = 4; mask <= 32; mask <<= 1)
#pragma unroll
        for (int m = 0; m < N_; ++m)
#pragma unroll
            for (int c = 0; c < 4; ++c)
                d[m][c] += __shfl_xor(d[m][c], mask);

    // Softmax over the 5 cavs, per pixel component.
    f4 wgt[N_];
#pragma unroll
    for (int c = 0; c < 4; ++c) {
        float dd[N_];
#pragma unroll
        for (int m = 0; m < N_; ++m) dd[m] = d[m][c] * 0.125f;  // / sqrt(64)
        float mx = dd[0];
#pragma unroll
        for (int m = 1; m < N_; ++m) mx = fmaxf(mx, dd[m]);
        float s = 0.f;
#pragma unroll
        for (int m = 0; m < N_; ++m) { dd[m] = __expf(dd[m] - mx); s += dd[m]; }
        const float inv = 1.0f / s;
#pragma unroll
        for (int m = 0; m < N_; ++m) wgt[m][c] = dd[m] * inv;
    }

    // out[b, cl*4+j, p..p+3] = sum_m wgt[m] * v[m][j], nt stores.
    float* ob = out + (size_t)b * (C_ * HW_) + (size_t)(cl * 4) * HW_ + p;
#pragma unroll
    for (int j = 0; j < 4; ++j) {
        f4 a = wgt[0] * v[0][j];
#pragma unroll
        for (int m = 1; m < N_; ++m) a += wgt[m] * v[m][j];
        __builtin_nontemporal_store(a, reinterpret_cast<f4*>(ob + (size_t)j * HW_));
    }
}

extern "C" void kernel_launch(void* const* d_in, const int* in_sizes, int n_in,
                              void* d_out, int out_size, void* d_ws, size_t ws_size,
                              hipStream_t stream) {
    const float* x = (const float*)d_in[0];
    float* out = (float*)d_out;
    // threads = B*HW/4 groups * 16 lanes = 1,612,800 = 6300 blocks of 256 exactly
    const int blocks = (B_ * HW_ / 4 * 16) / 256;
    where2comm_atten_kernel<<<blocks, 256, 0, stream>>>(x, out);
}

// Round 4
// 125.589 us; speedup vs baseline: 1.1501x; 1.1501x over previous
//
#include <hip/hip_runtime.h>

// Where2comm AttenFusion, ego-row-only. Long-run (256B) request version.
// x: (B=16, N=5, C=64, HW=25200) f32; out: (B, C, HW) f32.
// Per pixel p: dot[m] = <x[b,0,:,p], x[b,m,:,p]>/8; w = softmax(dot);
// out[b,:,p] = sum_m w[m]*x[b,m,:,p].
//
// Lane map (per 256-thread block = 4 waves = 64 consecutive pixels):
//   wave w (tid>>6): channel quarter, channels w*16 + cl*4 + j
//   cl = lane>>4 (0..3): chan-lane; j = 0..3: channel within lane
//   rg = lane&15: pixel-quad; block covers 16 quads = 64 px.
// Per load instruction: 16 rg-lanes x 16B = 256B contiguous per plane,
// 4 planes per instruction -> 2-3 memory requests per 256B run instead of
// 4 (the 64B-run version was request-rate-limited at ~78 Greq/s).
// Dot reduce: shfl_xor {16,32} within wave (16 ch), then one LDS exchange
// across the 4 waves (full 64-ch dot). Single pass, v[] register-resident.

#define B_ 16
#define N_ 5
#define C_ 64
#define HW_ 25200
#define PG_PER_IMG (HW_ / 4)   // 6300 pixel-quads per image

typedef float f4 __attribute__((ext_vector_type(4)));

__global__ __launch_bounds__(256) void where2comm_atten_kernel(
    const float* __restrict__ x, float* __restrict__ out)
{
    __shared__ f4 part[4][16][N_];   // [wave][rg][m] partial dots, 5.1 KB

    const int t  = threadIdx.x;
    const int w  = t >> 6;           // channel quarter 0..3
    const int l  = t & 63;
    const int rg = l & 15;           // pixel-quad within block
    const int cl = l >> 4;           // chan-lane 0..3

    const int pg  = blockIdx.x * 16 + rg;     // global pixel-quad
    const int b   = pg / PG_PER_IMG;
    const int px  = (pg - b * PG_PER_IMG) * 4; // pixel offset in image

    const int c0 = w * 16 + cl * 4;           // first of this lane's 4 channels
    const float* xb = x + (size_t)b * (N_ * C_ * HW_) + (size_t)c0 * HW_ + px;

    // Load 5 cavs x 4 channels x 4 pixels, all dwordx4, 256B runs/plane.
    f4 v[N_][4];
#pragma unroll
    for (int m = 0; m < N_; ++m)
#pragma unroll
        for (int j = 0; j < 4; ++j)
            v[m][j] = *reinterpret_cast<const f4*>(xb + (size_t)(m * C_ + j) * HW_);

    // Partial dots over this lane's 4 channels, then over the wave's 16.
    f4 d[N_];
#pragma unroll
    for (int m = 0; m < N_; ++m) {
        f4 acc = v[0][0] * v[m][0];
#pragma unroll
        for (int j = 1; j < 4; ++j) acc += v[0][j] * v[m][j];
#pragma unroll
        for (int c = 0; c < 4; ++c) {
            acc[c] += __shfl_xor(acc[c], 16);
            acc[c] += __shfl_xor(acc[c], 32);
        }
        d[m] = acc;
    }

    // Cross-wave exchange: each wave holds a 16-channel partial.
    if (cl == 0) {
#pragma unroll
        for (int m = 0; m < N_; ++m) part[w][rg][m] = d[m];
    }
    __syncthreads();

    f4 dd4[N_];
#pragma unroll
    for (int m = 0; m < N_; ++m) {
        f4 s = part[0][rg][m];
#pragma unroll
        for (int ww = 1; ww < 4; ++ww) s += part[ww][rg][m];
        dd4[m] = s;
    }

    // Softmax over the 5 cavs, per pixel component.
    f4 wgt[N_];
#pragma unroll
    for (int c = 0; c < 4; ++c) {
        float dd[N_];
#pragma unroll
        for (int m = 0; m < N_; ++m) dd[m] = dd4[m][c] * 0.125f;  // / sqrt(64)
        float mx = dd[0];
#pragma unroll
        for (int m = 1; m < N_; ++m) mx = fmaxf(mx, dd[m]);
        float s = 0.f;
#pragma unroll
        for (int m = 0; m < N_; ++m) { dd[m] = __expf(dd[m] - mx); s += dd[m]; }
        const float inv = 1.0f / s;
#pragma unroll
        for (int m = 0; m < N_; ++m) wgt[m][c] = dd[m] * inv;
    }

    // out[b, c0+j, px..px+3] = sum_m wgt[m] * v[m][j]; 256B store runs.
    float* ob = out + (size_t)b * (C_ * HW_) + (size_t)c0 * HW_ + px;
#pragma unroll
    for (int j = 0; j < 4; ++j) {
        f4 a = wgt[0] * v[0][j];
#pragma unroll
        for (int m = 1; m < N_; ++m) a += wgt[m] * v[m][j];
        *reinterpret_cast<f4*>(ob + (size_t)j * HW_) = a;
    }
}

extern "C" void kernel_launch(void* const* d_in, const int* in_sizes, int n_in,
                              void* d_out, int out_size, void* d_ws, size_t ws_size,
                              hipStream_t stream) {
    const float* x = (const float*)d_in[0];
    float* out = (float*)d_out;
    // one block per 16 pixel-quads: B*HW/64 = 6300 blocks
    const int blocks = (B_ * HW_) / 64;
    where2comm_atten_kernel<<<blocks, 256, 0, stream>>>(x, out);
}